// Round 1
// baseline (886.449 us; speedup 1.0000x reference)
//
#include <hip/hip_runtime.h>
#include <math.h>

#define NTOK 100000
#define C 1024
#define SN 18
#define H 4
#define DH 256
#define HSN 72
#define CLAMPV 10000.0f
#define EPSV 1e-8f

using short8 = __attribute__((ext_vector_type(8))) short;
using f32x4  = __attribute__((ext_vector_type(4))) float;

__device__ __forceinline__ float sanitize_f(float v) {
    if (isnan(v)) return 0.0f;
    return fminf(CLAMPV, fmaxf(-CLAMPV, v));
}
__device__ __forceinline__ unsigned short f2bf(float f) {
    unsigned int u = __float_as_uint(f);
    u = (u + 0x7FFFu + ((u >> 16) & 1u)) >> 16;
    return (unsigned short)u;
}
__device__ __forceinline__ float waveSum(float v) {
    #pragma unroll
    for (int o = 32; o > 0; o >>= 1) v += __shfl_down(v, o, 64);
    return v;
}
__device__ __forceinline__ float waveMax(float v) {
    #pragma unroll
    for (int o = 32; o > 0; o >>= 1) v = fmaxf(v, __shfl_down(v, o, 64));
    return v;
}

// q = rmsnorm(seeds, w_nq); one block per seed row
__global__ void k_qnorm(const float* __restrict__ seeds, const float* __restrict__ w_nq,
                        float* __restrict__ q) {
    int row = blockIdx.x, tid = threadIdx.x;
    const float* src = seeds + (size_t)row * C;
    float ss = 0.f;
    for (int c = tid; c < C; c += 256) { float v = sanitize_f(src[c]); ss += v * v; }
    __shared__ float red[4]; __shared__ float sSc;
    float w = waveSum(ss);
    if ((tid & 63) == 0) red[tid >> 6] = w;
    __syncthreads();
    if (tid == 0) {
        float t = red[0] + red[1] + red[2] + red[3];
        float rms = sqrtf(t / (float)C);
        sSc = 1.0f / (rms + EPSV);
    }
    __syncthreads();
    float sc = sSc;
    for (int c = tid; c < C; c += 256) q[(size_t)row * C + c] = w_nq[c] * sanitize_f(src[c]) * sc;
}

// qp[s][j] = (q[s]·Wq[j] + bq[j]) / sqrt(Dh); one wave per output
__global__ void k_qp(const float* __restrict__ q, const float* __restrict__ Wq,
                     const float* __restrict__ bq, float* __restrict__ qp) {
    int tid = threadIdx.x, wid = tid >> 6, lane = tid & 63;
    int out = blockIdx.x * 4 + wid;          // < 18432
    int s = out >> 10, j = out & 1023;
    const float* qrow = q + (size_t)s * C;
    const float* wrow = Wq + (size_t)j * C;
    float acc = 0.f;
    #pragma unroll
    for (int k = 0; k < 16; ++k) { int c = lane + 64 * k; acc = fmaf(qrow[c], wrow[c], acc); }
    acc = waveSum(acc);
    if (lane == 0) qp[out] = (acc + bq[j]) * 0.0625f;
}

// Ub[row][c] = bf16( (sum_d qp[s][h*DH+d] * Wk[h*DH+d][c]) * w_nkv[c] );  row = h*SN+s, rows 72..79 = 0
// bsc[row] (= qp[s,h,:]·bk[h,:]) folded in: computed by the ct==0 block of each row.
__global__ void k_U(const float* __restrict__ qp, const float* __restrict__ in_proj_w,
                    const float* __restrict__ in_proj_b, const float* __restrict__ w_nkv,
                    unsigned short* __restrict__ Ub, float* __restrict__ bsc) {
    int b = blockIdx.x, tid = threadIdx.x;
    int row = b >> 2, ct = b & 3;
    int c = ct * 256 + tid;
    __shared__ float qps[DH];
    __shared__ float red2[4];
    if (row < HSN) {
        int h = row / SN, s = row % SN;
        qps[tid] = qp[(size_t)s * C + h * DH + tid];
        __syncthreads();
        if (ct == 0) {                               // block-uniform branch
            float pb = qps[tid] * in_proj_b[C + h * DH + tid];
            float wsum = waveSum(pb);
            if ((tid & 63) == 0) red2[tid >> 6] = wsum;
            __syncthreads();
            if (tid == 0) bsc[row] = red2[0] + red2[1] + red2[2] + red2[3];
        }
        const float* Wk = in_proj_w + (size_t)C * C;
        float acc = 0.f;
        #pragma unroll 4
        for (int d = 0; d < DH; ++d) acc = fmaf(qps[d], Wk[(size_t)(h * DH + d) * C + c], acc);
        Ub[(size_t)row * C + c] = f2bf(acc * w_nkv[c]);
    } else {
        Ub[(size_t)row * C + c] = 0;
    }
}

// Pass A (MFMA): scores[hs][n] = scale_n * (U[hs]·x_san[n]) + bsc[hs]
// Also writes the sanitized-bf16 x cache (xb) for pass B when writeXb != 0.
__global__ __launch_bounds__(256, 3) void k_passA(const float* __restrict__ x,
    const unsigned short* __restrict__ Ub, const float* __restrict__ bsc,
    float* __restrict__ scaleG, float* __restrict__ scoresG,
    unsigned short* __restrict__ xbG, int writeXb) {
    __shared__ unsigned short xbL[8192];   // [ks2][tok128][c32]
    __shared__ unsigned short UbL[5120];   // [ks2][hs80][c32]
    __shared__ float bscLds[HSN];
    __shared__ float scaleLds[128];
    int tid = threadIdx.x;
    int n0 = blockIdx.x * 128;
    if (tid < HSN) bscLds[tid] = bsc[tid];
    int lane = tid & 63, wv = tid >> 6;
    int q = lane >> 4, mn = lane & 15;
    f32x4 acc[5][2];
    #pragma unroll
    for (int mt = 0; mt < 5; ++mt)
        #pragma unroll
        for (int nt = 0; nt < 2; ++nt) acc[mt][nt] = (f32x4){0.f, 0.f, 0.f, 0.f};
    float ss[8];
    #pragma unroll
    for (int i = 0; i < 8; ++i) ss[i] = 0.f;

    for (int kt = 0; kt < 16; ++kt) {
        __syncthreads();
        // stage x: 128 tok x 64 c, sanitize + bf16 (+ write-through to xb)
        #pragma unroll
        for (int i = 0; i < 8; ++i) {
            int f = tid + 256 * i;           // 0..2047
            int tok = f >> 4, cq = f & 15;
            int n = n0 + tok;
            float4 v = make_float4(0.f, 0.f, 0.f, 0.f);
            if (n < NTOK) v = *(const float4*)(x + (size_t)n * C + kt * 64 + 4 * cq);
            v.x = sanitize_f(v.x); v.y = sanitize_f(v.y);
            v.z = sanitize_f(v.z); v.w = sanitize_f(v.w);
            ss[i] += v.x * v.x + v.y * v.y + v.z * v.z + v.w * v.w;
            unsigned int lo = (unsigned int)f2bf(v.x) | ((unsigned int)f2bf(v.y) << 16);
            unsigned int hi = (unsigned int)f2bf(v.z) | ((unsigned int)f2bf(v.w) << 16);
            if (writeXb && n < NTOK)
                *(uint2*)&xbG[(size_t)n * C + kt * 64 + 4 * cq] = make_uint2(lo, hi);
            int ks = cq >> 3, c32 = (cq & 7) * 4;
            *(uint2*)&xbL[ks * 4096 + tok * 32 + c32] = make_uint2(lo, hi);
        }
        // stage U: 80 rows x 64 c (bf16 copy)
        #pragma unroll
        for (int u = 0; u < 5; ++u) {
            int idx = tid + 256 * u;         // 0..1279
            int row = idx >> 4, cq = idx & 15;
            int ks = cq >> 3, c32 = (cq & 7) * 4;
            uint2 w4 = *(const uint2*)(Ub + (size_t)row * C + kt * 64 + 4 * cq);
            *(uint2*)&UbL[ks * 2560 + row * 32 + c32] = w4;
        }
        __syncthreads();
        #pragma unroll
        for (int ks = 0; ks < 2; ++ks) {
            short8 a[5], b[2];
            #pragma unroll
            for (int mt = 0; mt < 5; ++mt)
                a[mt] = *(const short8*)&UbL[ks * 2560 + (mt * 16 + mn) * 32 + q * 8];
            #pragma unroll
            for (int nt = 0; nt < 2; ++nt)
                b[nt] = *(const short8*)&xbL[ks * 4096 + (wv * 32 + nt * 16 + mn) * 32 + q * 8];
            #pragma unroll
            for (int mt = 0; mt < 5; ++mt)
                #pragma unroll
                for (int nt = 0; nt < 2; ++nt)
                    acc[mt][nt] = __builtin_amdgcn_mfma_f32_16x16x32_bf16(a[mt], b[nt], acc[mt][nt], 0, 0, 0);
        }
    }
    __syncthreads();
    // sumsq reduce: thread (tid) holds partial for token (tid>>4)+16i, 16 partials/token
    float* ssS = (float*)xbL;                // 128*17 floats = 8704 B, fits
    #pragma unroll
    for (int i = 0; i < 8; ++i) ssS[((tid >> 4) + 16 * i) * 17 + (tid & 15)] = ss[i];
    __syncthreads();
    if (tid < 128) {
        float t = 0.f;
        #pragma unroll
        for (int k = 0; k < 16; ++k) t += ssS[tid * 17 + k];
        float rms = sqrtf(t / (float)C);
        float sc = 1.0f / (rms + EPSV);
        scaleLds[tid] = sc;
        if (n0 + tid < NTOK) scaleG[n0 + tid] = sc;
    }
    __syncthreads();
    #pragma unroll
    for (int mt = 0; mt < 5; ++mt) {
        #pragma unroll
        for (int nt = 0; nt < 2; ++nt) {
            int tl = wv * 32 + nt * 16 + mn;
            int n = n0 + tl;
            #pragma unroll
            for (int r = 0; r < 4; ++r) {
                int hs = mt * 16 + q * 4 + r;
                if (hs < HSN && n < NTOK)
                    scoresG[(size_t)hs * NTOK + n] = acc[mt][nt][r] * scaleLds[tl] + bscLds[hs];
            }
        }
    }
}

// softmax stats stage 1: per (hs, chunk-of-6272): partial max + partial sum-exp (float4)
__global__ void k_stats1(const float* __restrict__ scoresG, float* __restrict__ pm,
                         float* __restrict__ pd) {
    int ch = blockIdx.x, hs = blockIdx.y, tid = threadIdx.x;
    int nbeg = ch * 6272, nend = nbeg + 6272;
    if (nend > NTOK) nend = NTOK;
    const float* row = scoresG + (size_t)hs * NTOK;
    float m = -INFINITY;
    for (int n = nbeg + 4 * tid; n < nend; n += 1024) {
        float4 v = *(const float4*)(row + n);
        m = fmaxf(fmaxf(m, fmaxf(v.x, v.y)), fmaxf(v.z, v.w));
    }
    __shared__ float red[4]; __shared__ float sM;
    float w = waveMax(m);
    if ((tid & 63) == 0) red[tid >> 6] = w;
    __syncthreads();
    if (tid == 0) sM = fmaxf(fmaxf(red[0], red[1]), fmaxf(red[2], red[3]));
    __syncthreads();
    float mm = sM;
    float sum = 0.f;
    for (int n = nbeg + 4 * tid; n < nend; n += 1024) {
        float4 v = *(const float4*)(row + n);
        sum += __expf(v.x - mm) + __expf(v.y - mm) + __expf(v.z - mm) + __expf(v.w - mm);
    }
    __syncthreads();
    float ws2 = waveSum(sum);
    if ((tid & 63) == 0) red[tid >> 6] = ws2;
    __syncthreads();
    if (tid == 0) { pm[hs * 16 + ch] = mm; pd[hs * 16 + ch] = red[0] + red[1] + red[2] + red[3]; }
}

// w-precompute (stats stage 2 folded): wb[hs][n] = bf16( exp(s-m)*scale_n/den )
__global__ void k_w(const float* __restrict__ scoresG, const float* __restrict__ pm,
                    const float* __restrict__ pd, const float* __restrict__ scaleG,
                    unsigned short* __restrict__ wb) {
    int hs = blockIdx.y;
    __shared__ float sM, sI;
    if (threadIdx.x == 0) {
        float m = -INFINITY;
        #pragma unroll
        for (int i = 0; i < 16; ++i) m = fmaxf(m, pm[hs * 16 + i]);
        float s = 0.f;
        #pragma unroll
        for (int i = 0; i < 16; ++i) s += pd[hs * 16 + i] * __expf(pm[hs * 16 + i] - m);
        sM = m; sI = 1.0f / s;
    }
    __syncthreads();
    int n = (blockIdx.x * 256 + threadIdx.x) * 4;
    if (n >= NTOK) return;
    float mh = sM, ih = sI;
    float4 s4 = *(const float4*)(scoresG + (size_t)hs * NTOK + n);
    float4 c4 = *(const float4*)(scaleG + n);
    unsigned int lo = (unsigned int)f2bf(__expf(s4.x - mh) * c4.x * ih)
                    | ((unsigned int)f2bf(__expf(s4.y - mh) * c4.y * ih) << 16);
    unsigned int hi = (unsigned int)f2bf(__expf(s4.z - mh) * c4.z * ih)
                    | ((unsigned int)f2bf(__expf(s4.w - mh) * c4.w * ih) << 16);
    *(uint2*)&wb[(size_t)hs * NTOK + n] = make_uint2(lo, hi);
}

// Pass B (MFMA): Praw[hs][c] += sum_n wb[hs][n] * xb[n][c]  (both bf16, pure-copy staging)
template<int USE_XB>
__global__ __launch_bounds__(256, 3) void k_passB(const float* __restrict__ x,
    const unsigned short* __restrict__ xb, const unsigned short* __restrict__ wb,
    float* __restrict__ Praw) {
    __shared__ unsigned short xbTL[8192];   // [ks2][c128][tok32]
    __shared__ unsigned short wTL[5120];    // [ks2][hs80][tok32]
    int tid = threadIdx.x;
    // swizzle: all 8 c-tiles of one token-chunk land on one XCD (id mod 8 equal)
    int id = blockIdx.x;
    int r8 = id & 7, k8 = id >> 3;           // grid = 832
    int cb = k8 & 7;
    int tch = r8 + 8 * (k8 >> 3);
    if (tch >= 98) return;
    int c0 = cb * 128;
    int lane = tid & 63, wv = tid >> 6;
    int q = lane >> 4, mn = lane & 15;
    f32x4 acc[5][2];
    #pragma unroll
    for (int mt = 0; mt < 5; ++mt)
        #pragma unroll
        for (int nt = 0; nt < 2; ++nt) acc[mt][nt] = (f32x4){0.f, 0.f, 0.f, 0.f};

    for (int scn = 0; scn < 16; ++scn) {
        int n0 = tch * 1024 + scn * 64;
        __syncthreads();
        // stage w' tile: 80 hs x 64 tok (bf16, pure copy)
        #pragma unroll
        for (int u = 0; u < 5; ++u) {
            int idx = tid + 256 * u;          // 0..1279
            int hsr = idx >> 4, tq = idx & 15;
            int ks = tq >> 3, t32 = (tq & 7) * 4;
            int nbase = n0 + 4 * tq;
            uint2 w4 = make_uint2(0u, 0u);
            if (hsr < HSN && nbase < NTOK)
                w4 = *(const uint2*)&wb[(size_t)hsr * NTOK + nbase];
            *(uint2*)&wTL[ks * 2560 + hsr * 32 + t32] = w4;
        }
        // stage x^T tile: 128 c x 64 tok (transpose via registers)
        #pragma unroll
        for (int g = 0; g < 4; ++g) {
            int half = tid >> 7;              // = ks
            int cL = tid & 127;
            int tok0 = 32 * half + 8 * g;
            union { unsigned short u16[8]; short8 v; } pk;
            #pragma unroll
            for (int j = 0; j < 8; ++j) {
                int n = n0 + tok0 + j;
                if (USE_XB) {
                    pk.u16[j] = (n < NTOK) ? xb[(size_t)n * C + c0 + cL] : (unsigned short)0;
                } else {
                    float xv = 0.f;
                    if (n < NTOK) xv = x[(size_t)n * C + c0 + cL];
                    pk.u16[j] = f2bf(sanitize_f(xv));
                }
            }
            *(short8*)&xbTL[half * 4096 + cL * 32 + 8 * g] = pk.v;
        }
        __syncthreads();
        #pragma unroll
        for (int ks = 0; ks < 2; ++ks) {
            short8 a[5], b[2];
            #pragma unroll
            for (int mt = 0; mt < 5; ++mt)
                a[mt] = *(const short8*)&wTL[ks * 2560 + (mt * 16 + mn) * 32 + q * 8];
            #pragma unroll
            for (int nt = 0; nt < 2; ++nt)
                b[nt] = *(const short8*)&xbTL[ks * 4096 + (wv * 32 + nt * 16 + mn) * 32 + q * 8];
            #pragma unroll
            for (int mt = 0; mt < 5; ++mt)
                #pragma unroll
                for (int nt = 0; nt < 2; ++nt)
                    acc[mt][nt] = __builtin_amdgcn_mfma_f32_16x16x32_bf16(a[mt], b[nt], acc[mt][nt], 0, 0, 0);
        }
    }
    #pragma unroll
    for (int mt = 0; mt < 5; ++mt) {
        #pragma unroll
        for (int r = 0; r < 4; ++r) {
            int hs = mt * 16 + q * 4 + r;
            if (hs < HSN) {
                #pragma unroll
                for (int nt = 0; nt < 2; ++nt) {
                    int cc = c0 + wv * 32 + nt * 16 + mn;
                    atomicAdd(Praw + (size_t)hs * C + cc, acc[mt][nt][r]);
                }
            }
        }
    }
}

// o[s][hd] = sum_c Wv[hd][c] * w_nkv[c] * P[hs][c] + bv[hd]   (denom folded into w')
__global__ void k_o(const float* __restrict__ Praw, const float* __restrict__ in_proj_w,
                    const float* __restrict__ in_proj_b, const float* __restrict__ w_nkv,
                    float* __restrict__ o) {
    int tid = threadIdx.x, wid = tid >> 6, lane = tid & 63;
    int out = blockIdx.x * 4 + wid;                  // < 18432
    int s = out >> 10, hd = out & 1023;
    int h = hd >> 8;
    int hs = h * SN + s;
    const float* Wv = in_proj_w + (size_t)2 * C * C + (size_t)hd * C;
    const float* P = Praw + (size_t)hs * C;
    float acc = 0.f;
    #pragma unroll
    for (int k = 0; k < 16; ++k) { int c = lane + 64 * k; acc = fmaf(Wv[c], w_nkv[c] * P[c], acc); }
    acc = waveSum(acc);
    if (lane == 0) o[(size_t)s * C + hd] = acc + in_proj_b[2 * C + hd];
}

__global__ void k_obar(const float* __restrict__ o, float* __restrict__ obar) {
    int c = blockIdx.x * 256 + threadIdx.x;
    float acc = 0.f;
    #pragma unroll
    for (int s = 0; s < SN; ++s) acc += o[(size_t)s * C + c];
    obar[c] = acc * (1.0f / (float)SN);
}

// ctx[j] = sanitize(obar·Wout[j] + bout[j])
__global__ void k_out(const float* __restrict__ obar, const float* __restrict__ Wout,
                      const float* __restrict__ bout, float* __restrict__ outp) {
    int tid = threadIdx.x, wid = tid >> 6, lane = tid & 63;
    int j = blockIdx.x * 4 + wid;                    // < 1024
    float acc = 0.f;
    #pragma unroll
    for (int k = 0; k < 16; ++k) { int c = lane + 64 * k; acc = fmaf(obar[c], Wout[(size_t)j * C + c], acc); }
    acc = waveSum(acc);
    if (lane == 0) outp[j] = sanitize_f(acc + bout[j]);
}

extern "C" void kernel_launch(void* const* d_in, const int* in_sizes, int n_in,
                              void* d_out, int out_size, void* d_ws, size_t ws_size,
                              hipStream_t stream) {
    (void)in_sizes; (void)n_in; (void)out_size;
    const float* x         = (const float*)d_in[0];
    const float* seeds     = (const float*)d_in[1];
    const float* w_nq      = (const float*)d_in[2];
    const float* w_nkv     = (const float*)d_in[3];
    const float* in_proj_w = (const float*)d_in[4];
    const float* in_proj_b = (const float*)d_in[5];
    const float* out_proj_w = (const float*)d_in[6];
    const float* out_proj_b = (const float*)d_in[7];
    float* outp = (float*)d_out;

    float* ws     = (float*)d_ws;
    float* q      = ws;                  // 18432
    float* qp     = ws + 18432;          // 18432
    unsigned short* Ub = (unsigned short*)(ws + 36864);  // 80*1024 bf16
    float* bsc    = ws + 110592;         // 128
    float* scale  = ws + 110976;         // 100352
    float* pm     = ws + 211328;         // 1152
    float* pd     = ws + 212480;         // 1152
    float* scores = ws + 213632;         // 7200000
    float* Praw   = ws + 7413632;        // 73728
    float* o      = ws + 7487360;        // 18432
    float* obar   = ws + 7505792;        // 1024
    unsigned short* wb = (unsigned short*)(ws + 7506816);   // 72*100000 bf16 = 3.6M floats
    unsigned short* xb = (unsigned short*)(ws + 11110400);  // 100000*1024 bf16 = 51.2M floats
    // xb end = (11110400 + 51200000)*4 B = 249,241,600 B
    int useXb = (ws_size >= (size_t)249241600ull) ? 1 : 0;

    k_qnorm<<<SN, 256, 0, stream>>>(seeds, w_nq, q);
    k_qp<<<4608, 256, 0, stream>>>(q, in_proj_w, in_proj_b, qp);
    k_U<<<320, 256, 0, stream>>>(qp, in_proj_w, in_proj_b, w_nkv, Ub, bsc);
    k_passA<<<782, 256, 0, stream>>>(x, Ub, bsc, scale, scores, xb, useXb);
    k_stats1<<<dim3(16, HSN), 256, 0, stream>>>(scores, pm, pd);
    k_w<<<dim3(98, HSN), 256, 0, stream>>>(scores, pm, pd, scale, wb);
    hipMemsetAsync(Praw, 0, (size_t)HSN * C * sizeof(float), stream);
    if (useXb)
        k_passB<1><<<832, 256, 0, stream>>>(x, xb, wb, Praw);
    else
        k_passB<0><<<832, 256, 0, stream>>>(x, xb, wb, Praw);
    k_o<<<4608, 256, 0, stream>>>(Praw, in_proj_w, in_proj_b, w_nkv, o);
    k_obar<<<4, 256, 0, stream>>>(o, obar);
    k_out<<<256, 256, 0, stream>>>(obar, out_proj_w, out_proj_b, outp);
}